// Round 1
// baseline (636.925 us; speedup 1.0000x reference)
//
#include <hip/hip_runtime.h>
#include <hip/hip_bf16.h>
#include <math.h>

// Problem constants (fixed by the reference module)
#define BB 8
#define QQ 900
#define EE 256
#define NH 8
#define NL 4
#define NP 4
#define HD 32
#define SS 19560   // sum of H*W over levels

#define BM 64
#define BN 64
#define BK 16

// Generic fp32 tiled GEMM: C[M,N] = A[M,K] @ B[K,N] + bias[N] (+ res[M,N])
__global__ __launch_bounds__(256) void gemm_bias_res(
    const float* __restrict__ A, const float* __restrict__ Bm,
    const float* __restrict__ bias, const float* __restrict__ res,
    float* __restrict__ C, int M, int N, int K)
{
    __shared__ __align__(16) float As[BK][BM + 4];
    __shared__ __align__(16) float Bs[BK][BN + 4];

    const int t = threadIdx.x;
    const int row0 = blockIdx.y * BM;
    const int col0 = blockIdx.x * BN;

    const int tx = t & 15;        // 0..15 -> 4 cols each
    const int ty = t >> 4;        // 0..15 -> 4 rows each

    // A-tile load mapping: 64 rows x 4 float4 = 256 threads
    const int ar = t >> 2;
    const int ak = (t & 3) * 4;
    // B-tile load mapping: 16 rows x 16 float4 = 256 threads
    const int br = t >> 4;
    const int bc = (t & 15) * 4;

    float acc[4][4] = {};

    for (int k0 = 0; k0 < K; k0 += BK) {
        const int arow = row0 + ar;
        float4 av = make_float4(0.f, 0.f, 0.f, 0.f);
        if (arow < M)
            av = *(const float4*)(A + (size_t)arow * K + (k0 + ak));
        As[ak + 0][ar] = av.x;
        As[ak + 1][ar] = av.y;
        As[ak + 2][ar] = av.z;
        As[ak + 3][ar] = av.w;

        const float4 bv = *(const float4*)(Bm + (size_t)(k0 + br) * N + (col0 + bc));
        *(float4*)&Bs[br][bc] = bv;

        __syncthreads();

#pragma unroll
        for (int k = 0; k < BK; ++k) {
            const float4 a = *(const float4*)&As[k][ty * 4];
            const float4 b = *(const float4*)&Bs[k][tx * 4];
            acc[0][0] = fmaf(a.x, b.x, acc[0][0]);
            acc[0][1] = fmaf(a.x, b.y, acc[0][1]);
            acc[0][2] = fmaf(a.x, b.z, acc[0][2]);
            acc[0][3] = fmaf(a.x, b.w, acc[0][3]);
            acc[1][0] = fmaf(a.y, b.x, acc[1][0]);
            acc[1][1] = fmaf(a.y, b.y, acc[1][1]);
            acc[1][2] = fmaf(a.y, b.z, acc[1][2]);
            acc[1][3] = fmaf(a.y, b.w, acc[1][3]);
            acc[2][0] = fmaf(a.z, b.x, acc[2][0]);
            acc[2][1] = fmaf(a.z, b.y, acc[2][1]);
            acc[2][2] = fmaf(a.z, b.z, acc[2][2]);
            acc[2][3] = fmaf(a.z, b.w, acc[2][3]);
            acc[3][0] = fmaf(a.w, b.x, acc[3][0]);
            acc[3][1] = fmaf(a.w, b.y, acc[3][1]);
            acc[3][2] = fmaf(a.w, b.z, acc[3][2]);
            acc[3][3] = fmaf(a.w, b.w, acc[3][3]);
        }
        __syncthreads();
    }

    const int cbase = col0 + tx * 4;
    const float4 bset = *(const float4*)(bias + cbase);
#pragma unroll
    for (int i = 0; i < 4; ++i) {
        const int r = row0 + ty * 4 + i;
        if (r >= M) continue;
        float4 o;
        o.x = acc[i][0] + bset.x;
        o.y = acc[i][1] + bset.y;
        o.z = acc[i][2] + bset.z;
        o.w = acc[i][3] + bset.w;
        if (res) {
            const float4 rv = *(const float4*)(res + (size_t)r * N + cbase);
            o.x += rv.x; o.y += rv.y; o.z += rv.z; o.w += rv.w;
        }
        *(float4*)(C + (size_t)r * N + cbase) = o;
    }
}

// Per-(b,q) sampling: 256 threads = 8 heads x 32 HD lanes.
// out[bq][h*32+d] = sum_{l,p} attn * bilinear(v, loc)
__global__ __launch_bounds__(256) void msda_sample(
    const float* __restrict__ v,       // [B*S, 256]
    const float* __restrict__ off,     // [B*Q, 256]
    const float* __restrict__ logits,  // [B*Q, 128]
    const float* __restrict__ refp,    // [B*Q, 8]  (NL*2)
    float* __restrict__ out)           // [B*Q, 256]
{
    const int bq = blockIdx.x;
    const int b = bq / QQ;
    const int t = threadIdx.x;
    const int h = t >> 5;
    const int d = t & 31;

    __shared__ float s_off[256];
    __shared__ float s_log[128];
    __shared__ float s_w[128];
    __shared__ float s_ref[8];

    s_off[t] = off[(size_t)bq * 256 + t];
    if (t < 128) s_log[t] = logits[(size_t)bq * 128 + t];
    if (t < 8) s_ref[t] = refp[(size_t)bq * 8 + t];
    __syncthreads();

    if (t < 128) {
        const int hh = t >> 4;
        const float* lg = &s_log[hh * 16];
        float m = lg[0];
#pragma unroll
        for (int i = 1; i < 16; ++i) m = fmaxf(m, lg[i]);
        float ssum = 0.f;
#pragma unroll
        for (int i = 0; i < 16; ++i) ssum += __expf(lg[i] - m);
        s_w[t] = __expf(lg[t & 15] + (t & 15) * 0.f - m) / ssum;  // own element
    }
    __syncthreads();

    const int Hs[NL] = {92, 46, 23, 12};
    const int Ws[NL] = {160, 80, 40, 20};
    const int St[NL] = {0, 14720, 18400, 19320};

    const float* vb = v + (size_t)b * SS * 256 + h * HD + d;

    float acc = 0.f;
#pragma unroll
    for (int l = 0; l < NL; ++l) {
        const int Hl = Hs[l], Wl = Ws[l], st = St[l];
        const float rx = s_ref[l * 2 + 0];
        const float ry = s_ref[l * 2 + 1];
#pragma unroll
        for (int p = 0; p < NP; ++p) {
            const float ox = s_off[h * 32 + l * 8 + p * 2 + 0];
            const float oy = s_off[h * 32 + l * 8 + p * 2 + 1];
            const float x = fmaf(rx, (float)Wl, ox) - 0.5f;
            const float y = fmaf(ry, (float)Hl, oy) - 0.5f;
            const float xf = floorf(x);
            const float yf = floorf(y);
            const int x0 = (int)xf;
            const int y0 = (int)yf;
            const float wx = x - xf;
            const float wy = y - yf;
            const float w = s_w[h * 16 + l * 4 + p];

            const float w00 = w * (1.f - wy) * (1.f - wx);
            const float w01 = w * (1.f - wy) * wx;
            const float w10 = w * wy * (1.f - wx);
            const float w11 = w * wy * wx;

            const bool vy0 = (y0 >= 0) & (y0 < Hl);
            const bool vy1 = (y0 + 1 >= 0) & (y0 + 1 < Hl);
            const bool vx0 = (x0 >= 0) & (x0 < Wl);
            const bool vx1 = (x0 + 1 >= 0) & (x0 + 1 < Wl);

            if (vy0 & vx0) acc = fmaf(w00, vb[(size_t)(st + y0 * Wl + x0) * 256], acc);
            if (vy0 & vx1) acc = fmaf(w01, vb[(size_t)(st + y0 * Wl + x0 + 1) * 256], acc);
            if (vy1 & vx0) acc = fmaf(w10, vb[(size_t)(st + (y0 + 1) * Wl + x0) * 256], acc);
            if (vy1 & vx1) acc = fmaf(w11, vb[(size_t)(st + (y0 + 1) * Wl + x0 + 1) * 256], acc);
        }
    }
    out[(size_t)bq * 256 + t] = acc;
}

extern "C" void kernel_launch(void* const* d_in, const int* in_sizes, int n_in,
                              void* d_out, int out_size, void* d_ws, size_t ws_size,
                              hipStream_t stream) {
    const float* query  = (const float*)d_in[0];
    const float* value  = (const float*)d_in[1];
    const float* refp   = (const float*)d_in[2];
    // d_in[3] spatial_shapes (int32) -- constant, hardcoded
    const float* W_off  = (const float*)d_in[4];
    const float* b_off  = (const float*)d_in[5];
    const float* W_attn = (const float*)d_in[6];
    const float* b_attn = (const float*)d_in[7];
    const float* W_v    = (const float*)d_in[8];
    const float* b_v    = (const float*)d_in[9];
    const float* W_out  = (const float*)d_in[10];
    const float* b_out  = (const float*)d_in[11];
    float* out = (float*)d_out;

    float* ws = (float*)d_ws;
    float* v_ws    = ws;                          // B*S*256     = 40,058,880
    float* off_ws  = v_ws + (size_t)BB * SS * 256;   // B*Q*256  =  1,843,200
    float* log_ws  = off_ws + (size_t)BB * QQ * 256; // B*Q*128  =    921,600
    float* samp_ws = log_ws + (size_t)BB * QQ * 128; // B*Q*256  =  1,843,200

    const int Mv = BB * SS;   // 156480
    const int Mq = BB * QQ;   // 7200
    dim3 blk(256);

    // 1. value projection: v = value @ W_v + b_v
    gemm_bias_res<<<dim3(EE / BN, (Mv + BM - 1) / BM), blk, 0, stream>>>(
        value, W_v, b_v, nullptr, v_ws, Mv, EE, EE);
    // 2. sampling offsets: off = query @ W_off + b_off
    gemm_bias_res<<<dim3(EE / BN, (Mq + BM - 1) / BM), blk, 0, stream>>>(
        query, W_off, b_off, nullptr, off_ws, Mq, EE, EE);
    // 3. attention logits: logits = query @ W_attn + b_attn
    gemm_bias_res<<<dim3(128 / BN, (Mq + BM - 1) / BM), blk, 0, stream>>>(
        query, W_attn, b_attn, nullptr, log_ws, Mq, 128, EE);
    // 4. softmax + bilinear sampling + weighted sum
    msda_sample<<<dim3(Mq), blk, 0, stream>>>(v_ws, off_ws, log_ws, refp, samp_ws);
    // 5. output projection + residual: out = samp @ W_out + b_out + query
    gemm_bias_res<<<dim3(EE / BN, (Mq + BM - 1) / BM), blk, 0, stream>>>(
        samp_ws, W_out, b_out, query, out, Mq, EE, EE);
}

// Round 2
// 477.454 us; speedup vs baseline: 1.3340x; 1.3340x over previous
//
#include <hip/hip_runtime.h>
#include <hip/hip_bf16.h>
#include <math.h>

// Problem constants (fixed by the reference module)
#define BB 8
#define QQ 900
#define EE 256
#define NH 8
#define NL 4
#define NP 4
#define HD 32
#define SS 19560   // sum of H*W over levels

typedef short short8 __attribute__((ext_vector_type(8)));
typedef float f32x4 __attribute__((ext_vector_type(4)));

__device__ __forceinline__ unsigned short f2bf(float f) {
    __hip_bfloat16 h = __float2bfloat16(f);
    return *reinterpret_cast<unsigned short*>(&h);
}

// ---------------------------------------------------------------------------
// Value projection: C_bf16[M,256] = A_f32[M,256] @ W_f32[256,256] + bias
// MFMA 16x16x32 bf16, fp32 accumulate. Tile 128x64, BK=32, B staged whole-K.
// ---------------------------------------------------------------------------
#define VBM 128
#define VBN 64

__global__ __launch_bounds__(256) void gemm_v_bf16(
    const float* __restrict__ A, const float* __restrict__ W,
    const float* __restrict__ bias, unsigned short* __restrict__ C, int M)
{
    __shared__ short As[VBM][32 + 8];     // 128 x 40 shorts (pad: stride 80 B)
    __shared__ short Bs[VBN][256 + 8];    // 64 x 264 shorts (stride 528 B)

    const int t = threadIdx.x;
    const int col0 = blockIdx.x * VBN;
    const int row0 = blockIdx.y * VBM;

    // ---- stage B for ALL of K (once): W[k][col0..col0+63] -> Bs[c][k] ----
#pragma unroll
    for (int i = 0; i < 16; ++i) {
        const int cc = t + i * 256;     // 4096 float4-chunks
        const int k = cc >> 4;
        const int c4 = (cc & 15) * 4;
        const float4 wv = *(const float4*)(W + (size_t)k * 256 + col0 + c4);
        Bs[c4 + 0][k] = (short)f2bf(wv.x);
        Bs[c4 + 1][k] = (short)f2bf(wv.y);
        Bs[c4 + 2][k] = (short)f2bf(wv.z);
        Bs[c4 + 3][k] = (short)f2bf(wv.w);
    }

    const int w = t >> 6;         // wave 0..3 -> rows w*32 .. w*32+31
    const int ln = t & 63;
    const int quad = ln >> 4;     // 0..3
    const int m16 = ln & 15;      // 0..15
    const int wm = w * 32;

    const int rowa = t >> 2;      // A-staging: rows rowa, rowa+64
    const int kg = t & 3;         // k-group (8 floats each)

    f32x4 acc[2][4] = {};

    __syncthreads();   // Bs ready

    for (int ks = 0; ks < 8; ++ks) {
        const int k0 = ks * 32;
        // ---- stage A tile (fp32 -> bf16) ----
#pragma unroll
        for (int half = 0; half < 2; ++half) {
            const int row = rowa + half * 64;
            const int grow = row0 + row;
            float4 v0 = make_float4(0.f, 0.f, 0.f, 0.f);
            float4 v1 = make_float4(0.f, 0.f, 0.f, 0.f);
            if (grow < M) {
                const float* p = A + (size_t)grow * 256 + k0 + kg * 8;
                v0 = *(const float4*)p;
                v1 = *(const float4*)(p + 4);
            }
            short tmp[8];
            tmp[0] = (short)f2bf(v0.x); tmp[1] = (short)f2bf(v0.y);
            tmp[2] = (short)f2bf(v0.z); tmp[3] = (short)f2bf(v0.w);
            tmp[4] = (short)f2bf(v1.x); tmp[5] = (short)f2bf(v1.y);
            tmp[6] = (short)f2bf(v1.z); tmp[7] = (short)f2bf(v1.w);
            *(short8*)&As[row][kg * 8] = *(const short8*)tmp;
        }
        __syncthreads();

        // ---- MFMA: wave computes 32 rows x 64 cols ----
        short8 af0 = *(const short8*)&As[wm + m16][quad * 8];
        short8 af1 = *(const short8*)&As[wm + 16 + m16][quad * 8];
#pragma unroll
        for (int nt = 0; nt < 4; ++nt) {
            const short8 bfv = *(const short8*)&Bs[nt * 16 + m16][k0 + quad * 8];
            acc[0][nt] = __builtin_amdgcn_mfma_f32_16x16x32_bf16(af0, bfv, acc[0][nt], 0, 0, 0);
            acc[1][nt] = __builtin_amdgcn_mfma_f32_16x16x32_bf16(af1, bfv, acc[1][nt], 0, 0, 0);
        }
        __syncthreads();
    }

    // ---- epilogue: + bias, store bf16 ----
#pragma unroll
    for (int nt = 0; nt < 4; ++nt) {
        const int col = col0 + nt * 16 + m16;
        const float bsv = bias[col];
#pragma unroll
        for (int mt = 0; mt < 2; ++mt) {
#pragma unroll
            for (int r = 0; r < 4; ++r) {
                const int row = row0 + wm + mt * 16 + quad * 4 + r;
                if (row < M)
                    C[(size_t)row * 256 + col] = f2bf(acc[mt][nt][r] + bsv);
            }
        }
    }
}

// ---------------------------------------------------------------------------
// Generic fp32 tiled GEMM (small GEMMs): C = A@B + bias (+ res)
// ---------------------------------------------------------------------------
#define BM 64
#define BN 64
#define BK 16

__global__ __launch_bounds__(256) void gemm_bias_res(
    const float* __restrict__ A, const float* __restrict__ Bm,
    const float* __restrict__ bias, const float* __restrict__ res,
    float* __restrict__ C, int M, int N, int K)
{
    __shared__ __align__(16) float As[BK][BM + 4];
    __shared__ __align__(16) float Bs[BK][BN + 4];

    const int t = threadIdx.x;
    const int row0 = blockIdx.y * BM;
    const int col0 = blockIdx.x * BN;
    const int tx = t & 15;
    const int ty = t >> 4;
    const int ar = t >> 2;
    const int ak = (t & 3) * 4;
    const int br = t >> 4;
    const int bc = (t & 15) * 4;

    float acc[4][4] = {};

    for (int k0 = 0; k0 < K; k0 += BK) {
        const int arow = row0 + ar;
        float4 av = make_float4(0.f, 0.f, 0.f, 0.f);
        if (arow < M)
            av = *(const float4*)(A + (size_t)arow * K + (k0 + ak));
        As[ak + 0][ar] = av.x;
        As[ak + 1][ar] = av.y;
        As[ak + 2][ar] = av.z;
        As[ak + 3][ar] = av.w;
        *(float4*)&Bs[br][bc] = *(const float4*)(Bm + (size_t)(k0 + br) * N + (col0 + bc));
        __syncthreads();
#pragma unroll
        for (int k = 0; k < BK; ++k) {
            const float4 a = *(const float4*)&As[k][ty * 4];
            const float4 b = *(const float4*)&Bs[k][tx * 4];
            acc[0][0] = fmaf(a.x, b.x, acc[0][0]);
            acc[0][1] = fmaf(a.x, b.y, acc[0][1]);
            acc[0][2] = fmaf(a.x, b.z, acc[0][2]);
            acc[0][3] = fmaf(a.x, b.w, acc[0][3]);
            acc[1][0] = fmaf(a.y, b.x, acc[1][0]);
            acc[1][1] = fmaf(a.y, b.y, acc[1][1]);
            acc[1][2] = fmaf(a.y, b.z, acc[1][2]);
            acc[1][3] = fmaf(a.y, b.w, acc[1][3]);
            acc[2][0] = fmaf(a.z, b.x, acc[2][0]);
            acc[2][1] = fmaf(a.z, b.y, acc[2][1]);
            acc[2][2] = fmaf(a.z, b.z, acc[2][2]);
            acc[2][3] = fmaf(a.z, b.w, acc[2][3]);
            acc[3][0] = fmaf(a.w, b.x, acc[3][0]);
            acc[3][1] = fmaf(a.w, b.y, acc[3][1]);
            acc[3][2] = fmaf(a.w, b.z, acc[3][2]);
            acc[3][3] = fmaf(a.w, b.w, acc[3][3]);
        }
        __syncthreads();
    }

    const int cbase = col0 + tx * 4;
    const float4 bset = *(const float4*)(bias + cbase);
#pragma unroll
    for (int i = 0; i < 4; ++i) {
        const int r = row0 + ty * 4 + i;
        if (r >= M) continue;
        float4 o;
        o.x = acc[i][0] + bset.x;
        o.y = acc[i][1] + bset.y;
        o.z = acc[i][2] + bset.z;
        o.w = acc[i][3] + bset.w;
        if (res) {
            const float4 rv = *(const float4*)(res + (size_t)r * N + cbase);
            o.x += rv.x; o.y += rv.y; o.z += rv.z; o.w += rv.w;
        }
        *(float4*)(C + (size_t)r * N + cbase) = o;
    }
}

// ---------------------------------------------------------------------------
// Sampling: v in bf16, 128 threads = 8 heads x 16 lanes, 2 channels/lane.
// ---------------------------------------------------------------------------
__global__ __launch_bounds__(128) void msda_sample_bf16(
    const unsigned short* __restrict__ v,  // [B*S, 256] bf16
    const float* __restrict__ off,         // [B*Q, 256]
    const float* __restrict__ logits,      // [B*Q, 128]
    const float* __restrict__ refp,        // [B*Q, 8]
    float* __restrict__ out)               // [B*Q, 256]
{
    const int bq = blockIdx.x;
    const int b = bq / QQ;
    const int t = threadIdx.x;   // 0..127
    const int h = t >> 4;        // head 0..7
    const int d2 = t & 15;       // channel-pair 0..15

    __shared__ float s_off[256];
    __shared__ float s_log[128];
    __shared__ float s_w[128];
    __shared__ float s_ref[8];

    *(float2*)&s_off[t * 2] = *(const float2*)(off + (size_t)bq * 256 + t * 2);
    const float lg = logits[(size_t)bq * 128 + t];
    s_log[t] = lg;
    if (t < 8) s_ref[t] = refp[(size_t)bq * 8 + t];
    __syncthreads();

    {
        const float* l = &s_log[h * 16];
        float m = l[0];
#pragma unroll
        for (int i = 1; i < 16; ++i) m = fmaxf(m, l[i]);
        float ssum = 0.f;
#pragma unroll
        for (int i = 0; i < 16; ++i) ssum += __expf(l[i] - m);
        s_w[t] = __expf(lg - m) / ssum;
    }
    __syncthreads();

    const int Hs[NL] = {92, 46, 23, 12};
    const int Ws[NL] = {160, 80, 40, 20};
    const int St[NL] = {0, 14720, 18400, 19320};

    // base ptr for this (b, head, channel-pair); rows stride 256 bf16 = 512 B
    const unsigned short* vb = v + (size_t)b * SS * 256 + h * 32 + d2 * 2;

    float ax = 0.f, ay = 0.f;
#pragma unroll
    for (int l = 0; l < NL; ++l) {
        const int Hl = Hs[l], Wl = Ws[l], st = St[l];
        const float rx = s_ref[l * 2 + 0];
        const float ry = s_ref[l * 2 + 1];
#pragma unroll
        for (int p = 0; p < NP; ++p) {
            const float ox = s_off[h * 32 + l * 8 + p * 2 + 0];
            const float oy = s_off[h * 32 + l * 8 + p * 2 + 1];
            const float x = fmaf(rx, (float)Wl, ox) - 0.5f;
            const float y = fmaf(ry, (float)Hl, oy) - 0.5f;
            const float xf = floorf(x);
            const float yf = floorf(y);
            const int x0 = (int)xf;
            const int y0 = (int)yf;
            const float wx = x - xf;
            const float wy = y - yf;
            const float wt = s_w[h * 16 + l * 4 + p];

            const float w00 = wt * (1.f - wy) * (1.f - wx);
            const float w01 = wt * (1.f - wy) * wx;
            const float w10 = wt * wy * (1.f - wx);
            const float w11 = wt * wy * wx;

            const bool vy0 = (y0 >= 0) & (y0 < Hl);
            const bool vy1 = (y0 + 1 >= 0) & (y0 + 1 < Hl);
            const bool vx0 = (x0 >= 0) & (x0 < Wl);
            const bool vx1 = (x0 + 1 >= 0) & (x0 + 1 < Wl);

            if (vy0 & vx0) {
                const unsigned int u = *(const unsigned int*)(vb + (size_t)(st + y0 * Wl + x0) * 256);
                ax = fmaf(w00, __uint_as_float(u << 16), ax);
                ay = fmaf(w00, __uint_as_float(u & 0xffff0000u), ay);
            }
            if (vy0 & vx1) {
                const unsigned int u = *(const unsigned int*)(vb + (size_t)(st + y0 * Wl + x0 + 1) * 256);
                ax = fmaf(w01, __uint_as_float(u << 16), ax);
                ay = fmaf(w01, __uint_as_float(u & 0xffff0000u), ay);
            }
            if (vy1 & vx0) {
                const unsigned int u = *(const unsigned int*)(vb + (size_t)(st + (y0 + 1) * Wl + x0) * 256);
                ax = fmaf(w10, __uint_as_float(u << 16), ax);
                ay = fmaf(w10, __uint_as_float(u & 0xffff0000u), ay);
            }
            if (vy1 & vx1) {
                const unsigned int u = *(const unsigned int*)(vb + (size_t)(st + (y0 + 1) * Wl + x0 + 1) * 256);
                ax = fmaf(w11, __uint_as_float(u << 16), ax);
                ay = fmaf(w11, __uint_as_float(u & 0xffff0000u), ay);
            }
        }
    }
    float2 o; o.x = ax; o.y = ay;
    *(float2*)(out + (size_t)bq * 256 + t * 2) = o;
}

extern "C" void kernel_launch(void* const* d_in, const int* in_sizes, int n_in,
                              void* d_out, int out_size, void* d_ws, size_t ws_size,
                              hipStream_t stream) {
    const float* query  = (const float*)d_in[0];
    const float* value  = (const float*)d_in[1];
    const float* refp   = (const float*)d_in[2];
    const float* W_off  = (const float*)d_in[4];
    const float* b_off  = (const float*)d_in[5];
    const float* W_attn = (const float*)d_in[6];
    const float* b_attn = (const float*)d_in[7];
    const float* W_v    = (const float*)d_in[8];
    const float* b_v    = (const float*)d_in[9];
    const float* W_out  = (const float*)d_in[10];
    const float* b_out  = (const float*)d_in[11];
    float* out = (float*)d_out;

    // Workspace layout
    unsigned short* v_bf = (unsigned short*)d_ws;                 // B*S*256 bf16 = 80.1 MB
    char* base = (char*)d_ws + (size_t)BB * SS * 256 * sizeof(unsigned short);
    float* off_ws  = (float*)base;                                // B*Q*256
    float* log_ws  = off_ws + (size_t)BB * QQ * 256;              // B*Q*128
    float* samp_ws = log_ws + (size_t)BB * QQ * 128;              // B*Q*256

    const int Mv = BB * SS;   // 156480
    const int Mq = BB * QQ;   // 7200

    // 1. value projection (bf16 MFMA): v_bf = bf16(value @ W_v + b_v)
    gemm_v_bf16<<<dim3(EE / VBN, (Mv + VBM - 1) / VBM), dim3(256), 0, stream>>>(
        value, W_v, b_v, v_bf, Mv);
    // 2. sampling offsets: off = query @ W_off + b_off
    gemm_bias_res<<<dim3(EE / BN, (Mq + BM - 1) / BM), dim3(256), 0, stream>>>(
        query, W_off, b_off, nullptr, off_ws, Mq, EE, EE);
    // 3. attention logits
    gemm_bias_res<<<dim3(128 / BN, (Mq + BM - 1) / BM), dim3(256), 0, stream>>>(
        query, W_attn, b_attn, nullptr, log_ws, Mq, 128, EE);
    // 4. softmax + bilinear sampling + weighted sum
    msda_sample_bf16<<<dim3(Mq), dim3(128), 0, stream>>>(v_bf, off_ws, log_ws, refp, samp_ws);
    // 5. output projection + residual
    gemm_bias_res<<<dim3(EE / BN, (Mq + BM - 1) / BM), dim3(256), 0, stream>>>(
        samp_ws, W_out, b_out, query, out, Mq, EE, EE);
}